// Round 2
// baseline (1839.397 us; speedup 1.0000x reference)
//
#include <hip/hip_runtime.h>
#include <math.h>

// Problem constants (from reference)
#define LEVEL_W 512
#define DEPTH   16
#define NNODES  (LEVEL_W * DEPTH)     // 8192
#define DIN     512
#define HD      512
#define ED      200
#define NC      150
#define KDIM    (DIN + ED + HD)       // 1224
#define KPAD    1248                  // padded to multiple of 32
#define GDIM    (4 * HD)              // 2048
#define OUTROWS (NNODES - LEVEL_W)    // 7680
#define KT      48                    // k-chunk per LDS stage
#define KSLEN   624                   // KPAD/2 (split-K half)

__device__ __forceinline__ float sigmoidf_(float x) {
    return 1.0f / (1.0f + expf(-x));
}

// ---------------------------------------------------------------------------
// prep: build W_cat[KPAD][2048] = [Wx; Wh; zeros] and inv[order[i]] = i
// ---------------------------------------------------------------------------
__global__ __launch_bounds__(256) void prep_kernel(
    const float* __restrict__ Wx, const float* __restrict__ Wh,
    const int* __restrict__ order, float* __restrict__ W_cat,
    int* __restrict__ inv)
{
    int i4 = blockIdx.x * 256 + threadIdx.x;
    const int total4 = KPAD * GDIM / 4;
    if (i4 < total4) {
        int i = i4 * 4;
        int k = i >> 11;        // / 2048
        int j = i & (GDIM - 1);
        float4 v = make_float4(0.f, 0.f, 0.f, 0.f);
        if (k < DIN + ED)      v = *(const float4*)&Wx[k * GDIM + j];
        else if (k < KDIM)     v = *(const float4*)&Wh[(k - DIN - ED) * GDIM + j];
        W_cat[i + 0] = v.x; W_cat[i + 1] = v.y; W_cat[i + 2] = v.z; W_cat[i + 3] = v.w;
    }
    if (i4 < NNODES) inv[order[i4]] = i4;
}

// ---------------------------------------------------------------------------
// Per-level split-K GEMM partial: g_part[ks] = x[:, ksrange] @ W_cat[ksrange, :]
// Grid: 256 blocks, 256 threads. blockIdx decode:
//   group = bid & 15; row_tile = bid >> 4; strip = group >> 1; ks = group & 1
// (all 16 row_tiles of one (strip,ks) share bid%8 -> same XCD -> B strip stays
//  in that XCD's L2)
// Block tile: 32 rows x 256 cols, K-range KSLEN. Wave: 8 rows x 256 cols,
// lane: 4 cols. A read via wave-uniform ds_read_b128 (broadcast), B via
// per-lane ds_read_b128 -> ~2 LDS-cyc per 3 VALU-cyc (VALU-bound).
// ---------------------------------------------------------------------------
__global__ __launch_bounds__(256) void level_gemm_part(
    const float* __restrict__ features, const float* __restrict__ embed,
    const int* __restrict__ parent, const float* __restrict__ W_cat,
    const float* __restrict__ h_all, const int* __restrict__ cm_all,
    float* __restrict__ part, int off)
{
    __shared__ float As[KT][32];       // [kk][row]
    __shared__ float Bs[KT][256];      // [kk][col]
    __shared__ int   p_s[32], root_s[32], eidx_s[32];

    const int tid      = threadIdx.x;
    const int group    = blockIdx.x & 15;
    const int row_tile = blockIdx.x >> 4;
    const int strip    = group >> 1;
    const int ks       = group & 1;

    const int w    = tid >> 6;         // wave 0..3
    const int lane = tid & 63;

    if (tid < 32) {
        int r  = off + row_tile * 32 + tid;
        int p  = parent[r];
        int rt = (p < 0);
        p_s[tid]    = rt ? 0 : p;
        root_s[tid] = rt;
        eidx_s[tid] = rt ? 0 : (cm_all[rt ? 0 : p] + 1);
    }
    __syncthreads();

    float acc[8][4];
    #pragma unroll
    for (int r = 0; r < 8; ++r)
        #pragma unroll
        for (int c = 0; c < 4; ++c) acc[r][c] = 0.f;

    const int g_row0 = off + row_tile * 32;

    for (int kt0 = ks * KSLEN; kt0 < ks * KSLEN + KSLEN; kt0 += KT) {
        // ---- stage A (gathered [features | embed | h_par | 0]) ----
        // KT*32 floats = 384 float4s; i -> row=i&31, k-chunk=(i>>5)*4
        for (int i = tid; i < (KT * 32 / 4); i += 256) {
            int ar = i & 31;
            int kc = (i >> 5) * 4;
            int k  = kt0 + kc;
            float4 v = make_float4(0.f, 0.f, 0.f, 0.f);
            if (k < DIN) {
                v = *(const float4*)&features[(size_t)(g_row0 + ar) * DIN + k];
            } else if (k < DIN + ED) {
                v = *(const float4*)&embed[(size_t)eidx_s[ar] * ED + (k - DIN)];
            } else if (k < KDIM) {
                if (!root_s[ar])
                    v = *(const float4*)&h_all[(size_t)p_s[ar] * HD + (k - DIN - ED)];
            }
            As[kc + 0][ar] = v.x;
            As[kc + 1][ar] = v.y;
            As[kc + 2][ar] = v.z;
            As[kc + 3][ar] = v.w;
        }
        // ---- stage B ----
        // KT*256 floats = 3072 float4s; i -> kk=i>>6, col4=i&63
        for (int i = tid; i < (KT * 256 / 4); i += 256) {
            int kk = i >> 6;
            int c4 = (i & 63) * 4;
            float4 v = *(const float4*)&W_cat[(size_t)(kt0 + kk) * GDIM + strip * 256 + c4];
            *(float4*)&Bs[kk][c4] = v;
        }
        __syncthreads();

        // ---- compute ----
        #pragma unroll 8
        for (int kk = 0; kk < KT; ++kk) {
            float4 b4 = *(const float4*)&Bs[kk][lane * 4];
            float4 a0 = *(const float4*)&As[kk][w * 8];      // rows 0..3 (uniform)
            float4 a1 = *(const float4*)&As[kk][w * 8 + 4];  // rows 4..7 (uniform)
            acc[0][0] += a0.x * b4.x; acc[0][1] += a0.x * b4.y; acc[0][2] += a0.x * b4.z; acc[0][3] += a0.x * b4.w;
            acc[1][0] += a0.y * b4.x; acc[1][1] += a0.y * b4.y; acc[1][2] += a0.y * b4.z; acc[1][3] += a0.y * b4.w;
            acc[2][0] += a0.z * b4.x; acc[2][1] += a0.z * b4.y; acc[2][2] += a0.z * b4.z; acc[2][3] += a0.z * b4.w;
            acc[3][0] += a0.w * b4.x; acc[3][1] += a0.w * b4.y; acc[3][2] += a0.w * b4.z; acc[3][3] += a0.w * b4.w;
            acc[4][0] += a1.x * b4.x; acc[4][1] += a1.x * b4.y; acc[4][2] += a1.x * b4.z; acc[4][3] += a1.x * b4.w;
            acc[5][0] += a1.y * b4.x; acc[5][1] += a1.y * b4.y; acc[5][2] += a1.y * b4.z; acc[5][3] += a1.y * b4.w;
            acc[6][0] += a1.z * b4.x; acc[6][1] += a1.z * b4.y; acc[6][2] += a1.z * b4.z; acc[6][3] += a1.z * b4.w;
            acc[7][0] += a1.w * b4.x; acc[7][1] += a1.w * b4.y; acc[7][2] += a1.w * b4.z; acc[7][3] += a1.w * b4.w;
        }
        __syncthreads();
    }

    // ---- write partial tile ----
    const int c_base = strip * 256 + lane * 4;
    #pragma unroll
    for (int r = 0; r < 8; ++r) {
        int lrow = row_tile * 32 + w * 8 + r;
        float4 v = make_float4(acc[r][0], acc[r][1], acc[r][2], acc[r][3]);
        *(float4*)&part[((size_t)ks * LEVEL_W + lrow) * GDIM + c_base] = v;
    }
}

// ---------------------------------------------------------------------------
// Per-level reduce(partials) + bias + LSTM cell + dropout -> h_all, c_all
// Grid: 256 blocks x 256 threads; block = 2 rows; thread = 4 h-cols.
// ---------------------------------------------------------------------------
__global__ __launch_bounds__(256) void level_cell(
    const float* __restrict__ part, const float* __restrict__ bias,
    const float* __restrict__ dropout, const int* __restrict__ parent,
    float* __restrict__ h_all, float* __restrict__ c_all, int off)
{
    const int tid  = threadIdx.x;
    const int lrow = blockIdx.x * 2 + (tid >> 7);
    const int tg   = (tid & 127) * 4;
    const int grow = off + lrow;

    int p  = parent[grow];
    int rt = (p < 0);
    int pp = rt ? 0 : p;

    const float* P0 = part + (size_t)lrow * GDIM;
    const float* P1 = part + ((size_t)LEVEL_W + lrow) * GDIM;

    float4 gi = *(const float4*)&P0[0 * HD + tg];
    float4 gf = *(const float4*)&P0[1 * HD + tg];
    float4 gg = *(const float4*)&P0[2 * HD + tg];
    float4 go = *(const float4*)&P0[3 * HD + tg];
    float4 t;
    t = *(const float4*)&P1[0 * HD + tg]; gi.x += t.x; gi.y += t.y; gi.z += t.z; gi.w += t.w;
    t = *(const float4*)&P1[1 * HD + tg]; gf.x += t.x; gf.y += t.y; gf.z += t.z; gf.w += t.w;
    t = *(const float4*)&P1[2 * HD + tg]; gg.x += t.x; gg.y += t.y; gg.z += t.z; gg.w += t.w;
    t = *(const float4*)&P1[3 * HD + tg]; go.x += t.x; go.y += t.y; go.z += t.z; go.w += t.w;
    float4 bi = *(const float4*)&bias[0 * HD + tg];
    float4 bf = *(const float4*)&bias[1 * HD + tg];
    float4 bg = *(const float4*)&bias[2 * HD + tg];
    float4 bo = *(const float4*)&bias[3 * HD + tg];
    float4 cp = make_float4(0.f, 0.f, 0.f, 0.f);
    if (!rt) cp = *(const float4*)&c_all[(size_t)pp * HD + tg];
    float4 dm = *(const float4*)&dropout[tg];

    float c2[4], h2[4];
    {
        float giv[4] = {gi.x + bi.x, gi.y + bi.y, gi.z + bi.z, gi.w + bi.w};
        float gfv[4] = {gf.x + bf.x, gf.y + bf.y, gf.z + bf.z, gf.w + bf.w};
        float ggv[4] = {gg.x + bg.x, gg.y + bg.y, gg.z + bg.z, gg.w + bg.w};
        float gov[4] = {go.x + bo.x, go.y + bo.y, go.z + bo.z, go.w + bo.w};
        float cpv[4] = {cp.x, cp.y, cp.z, cp.w};
        float dmv[4] = {dm.x, dm.y, dm.z, dm.w};
        #pragma unroll
        for (int j = 0; j < 4; ++j) {
            float c = sigmoidf_(gfv[j]) * cpv[j] + sigmoidf_(giv[j]) * tanhf(ggv[j]);
            c2[j] = c;
            h2[j] = sigmoidf_(gov[j]) * tanhf(c) * dmv[j];
        }
    }
    *(float4*)&c_all[(size_t)grow * HD + tg] = make_float4(c2[0], c2[1], c2[2], c2[3]);
    *(float4*)&h_all[(size_t)grow * HD + tg] = make_float4(h2[0], h2[1], h2[2], h2[3]);
}

// ---------------------------------------------------------------------------
// Per-level dist = h @ out_W + out_b, argmax (first-max tie-break), scatter
// both dist row and commitment to permuted output positions.
// Grid: 128 blocks x 256 threads; 4 rows per block; one wave per row argmax.
// ---------------------------------------------------------------------------
__global__ __launch_bounds__(256) void level_dist(
    const float* __restrict__ h_all, const float* __restrict__ outW,
    const float* __restrict__ outb, const int* __restrict__ inv,
    float* __restrict__ d_out, int* __restrict__ cm_all, int off)
{
    __shared__ float h_s[4][512];
    __shared__ float dist_s[4][160];

    const int tid = threadIdx.x;
    const int r0  = blockIdx.x * 4;

    for (int i4 = tid; i4 < 512; i4 += 256) {
        int row = i4 >> 7;
        int k   = (i4 & 127) * 4;
        *(float4*)&h_s[row][k] =
            *(const float4*)&h_all[(size_t)(off + r0 + row) * HD + k];
    }
    __syncthreads();

    const int j = tid;
    if (j < NC) {
        float a0 = 0.f, a1 = 0.f, a2 = 0.f, a3 = 0.f;
        for (int k = 0; k < HD; ++k) {
            float w = outW[k * NC + j];
            a0 += h_s[0][k] * w;
            a1 += h_s[1][k] * w;
            a2 += h_s[2][k] * w;
            a3 += h_s[3][k] * w;
        }
        float bj = outb[j];
        dist_s[0][j] = a0 + bj;
        dist_s[1][j] = a1 + bj;
        dist_s[2][j] = a2 + bj;
        dist_s[3][j] = a3 + bj;
    }
    __syncthreads();

    if (j < NC) {
        #pragma unroll
        for (int r = 0; r < 4; ++r) {
            int orow = inv[off + r0 + r];
            if (orow < OUTROWS) d_out[(size_t)orow * NC + j] = dist_s[r][j];
        }
    }

    // argmax: one wave (64 lanes) per row
    const int r    = tid >> 6;
    const int lane = tid & 63;
    float best = -3.402823466e38f;
    int   bidx = 0x7fffffff;
    for (int jj = lane; jj < NC; jj += 64) {
        float v = dist_s[r][jj];
        if (v > best || (v == best && jj < bidx)) { best = v; bidx = jj; }
    }
    #pragma unroll
    for (int m = 32; m >= 1; m >>= 1) {
        float ov = __shfl_xor(best, m);
        int   oi = __shfl_xor(bidx, m);
        if (ov > best || (ov == best && oi < bidx)) { best = ov; bidx = oi; }
    }
    if (lane == 0) {
        int grow = off + r0 + r;
        cm_all[grow] = bidx;
        int orow = inv[grow];
        if (orow < OUTROWS) d_out[(size_t)OUTROWS * NC + orow] = (float)bidx;
    }
}

// ---------------------------------------------------------------------------
extern "C" void kernel_launch(void* const* d_in, const int* in_sizes, int n_in,
                              void* d_out, int out_size, void* d_ws, size_t ws_size,
                              hipStream_t stream)
{
    const float* features = (const float*)d_in[0];
    const float* embed    = (const float*)d_in[1];
    const float* Wx       = (const float*)d_in[2];
    const float* Wh       = (const float*)d_in[3];
    const float* bias     = (const float*)d_in[4];
    const float* outW     = (const float*)d_in[5];
    const float* outb     = (const float*)d_in[6];
    const float* dropout  = (const float*)d_in[7];
    const int*   parent   = (const int*)d_in[8];
    const int*   order    = (const int*)d_in[9];

    float* W_cat  = (float*)d_ws;                          // 1248*2048 floats (10.2 MB)
    float* h_all  = W_cat + (size_t)KPAD * GDIM;           // 8192*512 (16.8 MB)
    float* c_all  = h_all + (size_t)NNODES * HD;           // 8192*512 (16.8 MB)
    float* part   = c_all + (size_t)NNODES * HD;           // 2*512*2048 (8.4 MB)
    int*   cm_all = (int*)(part + (size_t)2 * LEVEL_W * GDIM);
    int*   inv    = cm_all + NNODES;

    float* out = (float*)d_out;

    const int prep_blocks = (KPAD * GDIM / 4 + 255) / 256;  // 2496
    prep_kernel<<<prep_blocks, 256, 0, stream>>>(Wx, Wh, order, W_cat, inv);

    for (int l = 0; l < DEPTH; ++l) {
        int off = l * LEVEL_W;
        level_gemm_part<<<256, 256, 0, stream>>>(
            features, embed, parent, W_cat, h_all, cm_all, part, off);
        level_cell<<<256, 256, 0, stream>>>(
            part, bias, dropout, parent, h_all, c_all, off);
        level_dist<<<128, 256, 0, stream>>>(
            h_all, outW, outb, inv, out, cm_all, off);
    }
}

// Round 5
// 829.089 us; speedup vs baseline: 2.2186x; 2.2186x over previous
//
#include <hip/hip_runtime.h>
#include <math.h>

#define LEVEL_W 512
#define DEPTH   16
#define NNODES  8192
#define DIN     512
#define HD      512
#define ED      200
#define NC      150
#define GDIM    2048
#define OUTROWS 7680
#define KH      512        // f-buffer K (features), also h K
#define KW      1024       // combined weight K: [Wh(0:512) | Wx(512:1024)]
#define NKC     16         // K-chunks of 64 over KW

typedef __attribute__((ext_vector_type(8))) short s8v;   // 8 bf16 (4 VGPRs)
typedef __attribute__((ext_vector_type(4))) float f4v;   // 4 fp32 acc

__device__ __forceinline__ unsigned short f2bf(float x) {
    unsigned int u = __float_as_uint(x);
    u += 0x7FFFu + ((u >> 16) & 1u);
    return (unsigned short)(u >> 16);
}
__device__ __forceinline__ float bf2f(unsigned short b) {
    return __uint_as_float(((unsigned int)b) << 16);
}
__device__ __forceinline__ float sigm(float x) { return 1.0f / (1.0f + expf(-x)); }

__device__ __forceinline__ void gl_lds16(const void* g, void* l) {
    __builtin_amdgcn_global_load_lds((const __attribute__((address_space(1))) void*)g,
                                     (__attribute__((address_space(3))) void*)l, 16, 0, 0);
}

// ---------------------------------------------------------------------------
// prep_w: combined W^T [2048 n''][1024 k] as bf16 hi/lo.
// n'' = hcs*64 + gate*16 + hcl  <->  orig col = gate*512 + hcs*16 + hcl.
// k 0..511 = Wh rows, k 512..1023 = Wx rows 0..511 (features part).
// 16B chunks XOR-swizzled within each 128B (64-elem) window, key = n'' & 7,
// so linear global_load_lds + XOR'd ds_read_b128 is conflict-free.
// grid 64 x 256: b>>5 selects half (0=Wh, 1=Wx), ns = b & 31.
// ---------------------------------------------------------------------------
__global__ __launch_bounds__(256) void prep_w(
    const float* __restrict__ Wx, const float* __restrict__ Wh,
    unsigned short* __restrict__ w_hi, unsigned short* __restrict__ w_lo)
{
    __shared__ float Wt[64][65];
    const int t   = threadIdx.x;
    const int b   = blockIdx.x;
    const int mat = b >> 5;             // 0 = Wh (k 0..511), 1 = Wx (k 512..1023)
    const int ns  = b & 31;
    const float* src = mat ? Wx : Wh;

    for (int kw = 0; kw < 8; ++kw) {
        __syncthreads();
        #pragma unroll
        for (int p = 0; p < 16; ++p) {
            int gl  = p >> 2;
            int kk  = (p & 3) * 16 + (t >> 4);
            int col = gl * 512 + ns * 16 + (t & 15);
            Wt[kk][gl * 16 + (t & 15)] = src[(size_t)(kw * 64 + kk) * GDIM + col];
        }
        __syncthreads();
        {
            int nl  = t >> 2;
            int cp  = t & 3;
            int nsg = ns * 64 + nl;
            int key = nsg & 7;
            __align__(16) unsigned short hv[16], lv[16];
            #pragma unroll
            for (int e = 0; e < 16; ++e) {
                float x = Wt[cp * 16 + e][nl];
                unsigned short h = f2bf(x);
                hv[e] = h;
                lv[e] = f2bf(x - bf2f(h));
            }
            size_t base = (size_t)nsg * KW + mat * 512 + kw * 64;
            int c0 = cp * 2, c1 = cp * 2 + 1;
            *(uint4*)&w_hi[base + ((c0 ^ key) * 8)] = *(const uint4*)&hv[0];
            *(uint4*)&w_hi[base + ((c1 ^ key) * 8)] = *(const uint4*)&hv[8];
            *(uint4*)&w_lo[base + ((c0 ^ key) * 8)] = *(const uint4*)&lv[0];
            *(uint4*)&w_lo[base + ((c1 ^ key) * 8)] = *(const uint4*)&lv[8];
        }
    }
}

// ---------------------------------------------------------------------------
// prep_feat: features -> f_hi/f_lo bf16 [8192][512], chunk-swizzled (key r&7);
// also inv[order[i]] = i.
// ---------------------------------------------------------------------------
__global__ __launch_bounds__(256) void prep_feat(
    const float* __restrict__ features, const int* __restrict__ order,
    unsigned short* __restrict__ f_hi, unsigned short* __restrict__ f_lo,
    int* __restrict__ inv)
{
    int i = blockIdx.x * 256 + threadIdx.x;      // 262144 threads
    {
        int r  = i >> 5;
        int k0 = (i & 31) * 16;
        const float* srcp = features + (size_t)r * DIN + k0;
        __align__(16) unsigned short hv[16], lv[16];
        #pragma unroll
        for (int e = 0; e < 16; ++e) {
            float x = srcp[e];
            unsigned short h = f2bf(x);
            hv[e] = h;
            lv[e] = f2bf(x - bf2f(h));
        }
        int key = r & 7;
        int c0  = (k0 >> 3) & 7;
        size_t base = (size_t)r * KH + (k0 & ~63);
        *(uint4*)&f_hi[base + ((c0 ^ key) * 8)]       = *(const uint4*)&hv[0];
        *(uint4*)&f_hi[base + (((c0 + 1) ^ key) * 8)] = *(const uint4*)&hv[8];
        *(uint4*)&f_lo[base + ((c0 ^ key) * 8)]       = *(const uint4*)&lv[0];
        *(uint4*)&f_lo[base + (((c0 + 1) ^ key) * 8)] = *(const uint4*)&lv[8];
    }
    if (i < NNODES) inv[order[i]] = i;
}

// ---------------------------------------------------------------------------
// prep_embed: g_embed[e][n''] = embed[e]·Wx[512:712][orig(n'')] + b[orig(n'')]
// (bias folded in; e = 0..150).  fp32.
// ---------------------------------------------------------------------------
__global__ __launch_bounds__(128) void prep_embed(
    const float* __restrict__ embed, const float* __restrict__ Wx,
    const float* __restrict__ bvec, float* __restrict__ g_embed)
{
    int e    = blockIdx.y;
    int np   = blockIdx.x * 128 + threadIdx.x;
    int gate = (np >> 4) & 3, hcs = np >> 6, hcl = np & 15;
    int col  = gate * 512 + hcs * 16 + hcl;
    float acc = bvec[col];
    const float* er = embed + (size_t)e * ED;
    for (int k = 0; k < ED; ++k)
        acc += er[k] * Wx[(size_t)(DIN + k) * GDIM + col];
    g_embed[(size_t)e * GDIM + np] = acc;
}

// ---------------------------------------------------------------------------
// gemm_h_cell: per level, K=1024 fused GEMM + LSTM cell.
//   g = [h_par | features_row] @ [Wh; Wx]^T  (bf16x2 split, 3 products)
// A k-chunks 0..7: fp32 gather of parent h, split hi/lo, swizzled ds_write.
// A k-chunks 8..15: global_load_lds from pre-split/pre-swizzled f_hi/f_lo.
// B: global_load_lds from pre-split/pre-swizzled w_hi/w_lo (K-stride 1024).
// Block: 32 rows x 64 n'' (16 hcols x 4 gates), 2 waves (16 rows each);
// each lane ends with all 4 gates for 4 rows x 1 hcol -> cell in-register.
// grid dim3(32 ns, 16 mt) = 512 blocks = 2/CU.
// ---------------------------------------------------------------------------
__global__ __launch_bounds__(128) void gemm_h_cell(
    float* h_all, float* c_all,
    const int* __restrict__ parent, const int* __restrict__ cm_all,
    const unsigned short* __restrict__ w_hi, const unsigned short* __restrict__ w_lo,
    const unsigned short* __restrict__ f_hi, const unsigned short* __restrict__ f_lo,
    const float* __restrict__ g_embed, const float* __restrict__ dropout, int off)
{
    __shared__ unsigned short Ah[32 * 64], Al[32 * 64], Bh[64 * 64], Bl[64 * 64];
    __shared__ int p_s[32], rt_s[32], ei_s[32];
    const int t = threadIdx.x, w = t >> 6, lane = t & 63;
    const int ns = blockIdx.x, mt = blockIdx.y;
    const int grow0 = off + mt * 32;

    if (t < 32) {
        int p  = parent[grow0 + t];
        int rt = (p < 0) ? 1 : 0;
        p_s[t]  = rt ? 0 : p;
        rt_s[t] = rt;
        ei_s[t] = rt ? 0 : (cm_all[rt ? 0 : p] + 1);
    }
    __syncthreads();

    f4v acc[4];
    #pragma unroll
    for (int i = 0; i < 4; ++i) acc[i] = (f4v){0.f, 0.f, 0.f, 0.f};

    const int ar  = t >> 2;            // 0..31 (A gather row)
    const int aq  = t & 3;             // quarter of the 64-elem window
    const int ap  = p_s[ar];
    const int art = rt_s[ar];
    const float* asrc = h_all + (size_t)ap * HD + aq * 16;
    const int akey = ar & 7;
    const int ac0  = aq * 2;

    for (int kc = 0; kc < NKC; ++kc) {
        if (kc < 8) {
            // ---- A from parent h: fp32 gather -> hi/lo split -> swizzled write
            float x[16];
            if (art) {
                #pragma unroll
                for (int e = 0; e < 16; ++e) x[e] = 0.f;
            } else {
                const float4* s4 = (const float4*)(asrc + kc * 64);
                float4 v0 = s4[0], v1 = s4[1], v2 = s4[2], v3 = s4[3];
                x[0] = v0.x; x[1] = v0.y; x[2] = v0.z; x[3] = v0.w;
                x[4] = v1.x; x[5] = v1.y; x[6] = v1.z; x[7] = v1.w;
                x[8] = v2.x; x[9] = v2.y; x[10] = v2.z; x[11] = v2.w;
                x[12] = v3.x; x[13] = v3.y; x[14] = v3.z; x[15] = v3.w;
            }
            __align__(16) unsigned short hv[16], lv[16];
            #pragma unroll
            for (int e = 0; e < 16; ++e) {
                unsigned short h = f2bf(x[e]);
                hv[e] = h;
                lv[e] = f2bf(x[e] - bf2f(h));
            }
            *(uint4*)&Ah[ar * 64 + ((ac0 ^ akey) * 8)]       = *(const uint4*)&hv[0];
            *(uint4*)&Ah[ar * 64 + (((ac0 + 1) ^ akey) * 8)] = *(const uint4*)&hv[8];
            *(uint4*)&Al[ar * 64 + ((ac0 ^ akey) * 8)]       = *(const uint4*)&lv[0];
            *(uint4*)&Al[ar * 64 + (((ac0 + 1) ^ akey) * 8)] = *(const uint4*)&lv[8];
        } else {
            // ---- A from features: direct async copy of pre-swizzled planes
            #pragma unroll
            for (int q = 0; q < 2; ++q) {
                int ia  = w * 2 + q;                       // 0..3, wave-uniform
                int row = ia * 8 + (lane >> 3);            // 0..31
                size_t aoff = ((size_t)(grow0 + row) * KH + (kc - 8) * 64) * 2
                              + (lane & 7) * 16;
                gl_lds16((const char*)f_hi + aoff, (char*)Ah + ia * 1024);
                gl_lds16((const char*)f_lo + aoff, (char*)Al + ia * 1024);
            }
        }
        // ---- B stage: async copy from pre-swizzled combined weights
        #pragma unroll
        for (int q = 0; q < 4; ++q) {
            int ib  = w * 4 + q;                           // 0..7, wave-uniform
            int row = ib * 8 + (lane >> 3);                // 0..63
            size_t boff = ((size_t)(ns * 64 + row) * KW + kc * 64) * 2
                          + (lane & 7) * 16;
            gl_lds16((const char*)w_hi + boff, (char*)Bh + ib * 1024);
            gl_lds16((const char*)w_lo + boff, (char*)Bl + ib * 1024);
        }
        __syncthreads();
        // ---- compute: 2 half-chunks x 4 gate-blocks x 3 split-products
        #pragma unroll
        for (int s = 0; s < 2; ++s) {
            int arow = w * 16 + (lane & 15);
            int ach  = s * 4 + (lane >> 4);
            s8v ahv = *(const s8v*)&Ah[arow * 64 + ((ach ^ (arow & 7)) * 8)];
            s8v alv = *(const s8v*)&Al[arow * 64 + ((ach ^ (arow & 7)) * 8)];
            #pragma unroll
            for (int fn = 0; fn < 4; ++fn) {
                int brow = fn * 16 + (lane & 15);
                s8v bhv = *(const s8v*)&Bh[brow * 64 + ((ach ^ (brow & 7)) * 8)];
                s8v blv = *(const s8v*)&Bl[brow * 64 + ((ach ^ (brow & 7)) * 8)];
                acc[fn] = __builtin_amdgcn_mfma_f32_16x16x32_bf16(ahv, bhv, acc[fn], 0, 0, 0);
                acc[fn] = __builtin_amdgcn_mfma_f32_16x16x32_bf16(ahv, blv, acc[fn], 0, 0, 0);
                acc[fn] = __builtin_amdgcn_mfma_f32_16x16x32_bf16(alv, bhv, acc[fn], 0, 0, 0);
            }
        }
        __syncthreads();
    }

    // ---- fused epilogue: g = C + g_embed(+bias) -> LSTM cell -> h, c
    const int hcl  = lane & 15;
    const int hcol = ns * 16 + hcl;
    const float dm = dropout[hcol];
    #pragma unroll
    for (int j = 0; j < 4; ++j) {
        int lr   = w * 16 + (lane >> 4) * 4 + j;
        int grow = grow0 + lr;
        const float* gep = g_embed + (size_t)ei_s[lr] * GDIM + ns * 64;
        float gi = acc[0][j] + gep[0 * 16 + hcl];
        float gf = acc[1][j] + gep[1 * 16 + hcl];
        float gg = acc[2][j] + gep[2 * 16 + hcl];
        float go = acc[3][j] + gep[3 * 16 + hcl];
        float cpar = rt_s[lr] ? 0.f : c_all[(size_t)p_s[lr] * HD + hcol];
        float c2 = sigm(gf) * cpar + sigm(gi) * tanhf(gg);
        float h2 = sigm(go) * tanhf(c2) * dm;
        c_all[(size_t)grow * HD + hcol] = c2;
        h_all[(size_t)grow * HD + hcol] = h2;
    }
}

// ---------------------------------------------------------------------------
// level_dist: dist = h @ out_W + out_b (fp32), argmax (first-max tie-break),
// scatter dist row + commitment to permuted output positions.
// ---------------------------------------------------------------------------
__global__ __launch_bounds__(256) void level_dist(
    const float* __restrict__ h_all, const float* __restrict__ outW,
    const float* __restrict__ outb, const int* __restrict__ inv,
    float* __restrict__ d_out, int* __restrict__ cm_all, int off)
{
    __shared__ float h_s[4][512];
    __shared__ float dist_s[4][160];

    const int tid = threadIdx.x;
    const int r0  = blockIdx.x * 4;

    for (int i4 = tid; i4 < 512; i4 += 256) {
        int row = i4 >> 7;
        int k   = (i4 & 127) * 4;
        *(float4*)&h_s[row][k] =
            *(const float4*)&h_all[(size_t)(off + r0 + row) * HD + k];
    }
    __syncthreads();

    const int j = tid;
    if (j < NC) {
        float a0 = 0.f, a1 = 0.f, a2 = 0.f, a3 = 0.f;
        for (int k = 0; k < HD; ++k) {
            float w = outW[k * NC + j];
            a0 += h_s[0][k] * w;
            a1 += h_s[1][k] * w;
            a2 += h_s[2][k] * w;
            a3 += h_s[3][k] * w;
        }
        float bj = outb[j];
        dist_s[0][j] = a0 + bj;
        dist_s[1][j] = a1 + bj;
        dist_s[2][j] = a2 + bj;
        dist_s[3][j] = a3 + bj;
    }
    __syncthreads();

    if (j < NC) {
        #pragma unroll
        for (int r = 0; r < 4; ++r) {
            int orow = inv[off + r0 + r];
            if (orow < OUTROWS) d_out[(size_t)orow * NC + j] = dist_s[r][j];
        }
    }

    const int r    = tid >> 6;
    const int lane = tid & 63;
    float best = -3.402823466e38f;
    int   bidx = 0x7fffffff;
    for (int jj = lane; jj < NC; jj += 64) {
        float v = dist_s[r][jj];
        if (v > best || (v == best && jj < bidx)) { best = v; bidx = jj; }
    }
    #pragma unroll
    for (int m = 32; m >= 1; m >>= 1) {
        float ov = __shfl_xor(best, m);
        int   oi = __shfl_xor(bidx, m);
        if (ov > best || (ov == best && oi < bidx)) { best = ov; bidx = oi; }
    }
    if (lane == 0) {
        int grow = off + r0 + r;
        cm_all[grow] = bidx;
        int orow = inv[grow];
        if (orow < OUTROWS) d_out[(size_t)OUTROWS * NC + orow] = (float)bidx;
    }
}

// ---------------------------------------------------------------------------
extern "C" void kernel_launch(void* const* d_in, const int* in_sizes, int n_in,
                              void* d_out, int out_size, void* d_ws, size_t ws_size,
                              hipStream_t stream)
{
    const float* features = (const float*)d_in[0];
    const float* embed    = (const float*)d_in[1];
    const float* Wx       = (const float*)d_in[2];
    const float* Wh       = (const float*)d_in[3];
    const float* bias     = (const float*)d_in[4];
    const float* outW     = (const float*)d_in[5];
    const float* outb     = (const float*)d_in[6];
    const float* dropout  = (const float*)d_in[7];
    const int*   parent   = (const int*)d_in[8];
    const int*   order    = (const int*)d_in[9];

    char* p = (char*)d_ws;
    unsigned short* w_hi   = (unsigned short*)p; p += (size_t)GDIM * KW * 2;   // 4MB
    unsigned short* w_lo   = (unsigned short*)p; p += (size_t)GDIM * KW * 2;   // 4MB
    unsigned short* f_hi   = (unsigned short*)p; p += (size_t)NNODES * KH * 2; // 8MB
    unsigned short* f_lo   = (unsigned short*)p; p += (size_t)NNODES * KH * 2; // 8MB
    float*          g_emb  = (float*)p;          p += (size_t)(NC + 2) * GDIM * 4;
    float*          h_all  = (float*)p;          p += (size_t)NNODES * HD * 4; // 16.8MB
    float*          c_all  = (float*)p;          p += (size_t)NNODES * HD * 4; // 16.8MB
    int*            cm_all = (int*)p;            p += (size_t)NNODES * 4;
    int*            inv    = (int*)p;            p += (size_t)NNODES * 4;

    float* out = (float*)d_out;

    prep_w<<<64, 256, 0, stream>>>(Wx, Wh, w_hi, w_lo);
    prep_feat<<<1024, 256, 0, stream>>>(features, order, f_hi, f_lo, inv);
    prep_embed<<<dim3(16, NC + 1), 128, 0, stream>>>(embed, Wx, bias, g_emb);

    for (int l = 0; l < DEPTH; ++l) {
        int off = l * LEVEL_W;
        gemm_h_cell<<<dim3(32, 16), 128, 0, stream>>>(
            h_all, c_all, parent, cm_all, w_hi, w_lo, f_hi, f_lo, g_emb, dropout, off);
        level_dist<<<128, 256, 0, stream>>>(
            h_all, outW, outb, inv, out, cm_all, off);
    }
}